// Round 1
// baseline (575.753 us; speedup 1.0000x reference)
//
#include <hip/hip_runtime.h>
#include <math.h>

#define NEG_SLOPE 0.2f

// ---------------- CSR build ----------------

__global__ void count_dst(const int* __restrict__ dst, int* __restrict__ counts, int E) {
    int e = blockIdx.x * blockDim.x + threadIdx.x;
    if (e < E) atomicAdd(&counts[dst[e]], 1);
}

// block 256 threads, 1024 elements per block: exclusive scan within block
__global__ void scan_local(const int* __restrict__ counts, int* __restrict__ indptr,
                           int* __restrict__ blocksums, int n) {
    __shared__ int sdata[256];
    int b = blockIdx.x, t = threadIdx.x;
    int base = b * 1024 + t * 4;
    int v[4];
    int sum = 0;
#pragma unroll
    for (int j = 0; j < 4; j++) {
        int idx = base + j;
        v[j] = (idx < n) ? counts[idx] : 0;
        sum += v[j];
    }
    sdata[t] = sum;
    __syncthreads();
    for (int o = 1; o < 256; o <<= 1) {
        int u = 0;
        if (t >= o) u = sdata[t - o];
        __syncthreads();
        if (t >= o) sdata[t] += u;
        __syncthreads();
    }
    int excl = (t > 0) ? sdata[t - 1] : 0;
    int run = excl;
#pragma unroll
    for (int j = 0; j < 4; j++) {
        int idx = base + j;
        if (idx < n) indptr[idx] = run;
        run += v[j];
    }
    if (t == 255) blocksums[b] = sdata[255];
}

__global__ void scan_carry(int* __restrict__ blocksums, int nb) {
    int t = threadIdx.x;  // 64 threads, nb <= 64
    int v = (t < nb) ? blocksums[t] : 0;
    int orig = v;
#pragma unroll
    for (int o = 1; o < 64; o <<= 1) {
        int u = __shfl_up(v, o);
        if (t >= o) v += u;
    }
    if (t < nb) blocksums[t] = v - orig;  // exclusive
}

__global__ void scan_add(int* __restrict__ indptr, const int* __restrict__ blocksums,
                         int n, int Etot) {
    int b = blockIdx.x, t = threadIdx.x;
    int base = b * 1024 + t * 4;
    int add = blocksums[b];
#pragma unroll
    for (int j = 0; j < 4; j++) {
        int idx = base + j;
        if (idx < n) indptr[idx] += add;
    }
    if (b == 0 && t == 0) indptr[n] = Etot;
}

__global__ void fill_csr(const int* __restrict__ dst, int* __restrict__ cursor,
                         int* __restrict__ eidx, int E) {
    int e = blockIdx.x * blockDim.x + threadIdx.x;
    if (e < E) {
        int p = atomicAdd(&cursor[dst[e]], 1);
        eidx[p] = e;
    }
}

// ---------------- fp32 GEMM: C[M][N] = A[M][K] * B[N][K]^T ----------------
// block 256 threads (16x16), tile 64x64, BK=32, each thread 4x4 micro-tile

__global__ __launch_bounds__(256) void gemm_nt(const float* __restrict__ A,
                                               const float* __restrict__ B,
                                               float* __restrict__ C,
                                               int M, int N, int K) {
    __shared__ float as[64][36];    // [row][k], pad to 36 (144B rows, 16B aligned)
    __shared__ float bs[32][64];    // [k][col]
    int t = threadIdx.x;
    int tx = t & 15, ty = t >> 4;
    int row0 = blockIdx.x * 64;
    int col0 = blockIdx.y * 64;
    int lr = t >> 2;            // 0..63
    int lk = (t & 3) * 8;       // 0,8,16,24

    float acc[4][4] = {};

    for (int k0 = 0; k0 < K; k0 += 32) {
        // load A tile 64x32 (clamp OOB rows; their results are never stored)
        {
            int gr = row0 + lr;
            int grc = gr < M ? gr : M - 1;
            const float4* pa = (const float4*)(A + (size_t)grc * K + k0 + lk);
            float4 v0 = pa[0];
            float4 v1 = pa[1];
            *(float4*)&as[lr][lk] = v0;
            *(float4*)&as[lr][lk + 4] = v1;
        }
        // load B tile 64 cols x 32 k, transpose into [k][col]
        {
            const float4* pb = (const float4*)(B + (size_t)(col0 + lr) * K + k0 + lk);
            float4 v0 = pb[0];
            float4 v1 = pb[1];
            bs[lk + 0][lr] = v0.x; bs[lk + 1][lr] = v0.y;
            bs[lk + 2][lr] = v0.z; bs[lk + 3][lr] = v0.w;
            bs[lk + 4][lr] = v1.x; bs[lk + 5][lr] = v1.y;
            bs[lk + 6][lr] = v1.z; bs[lk + 7][lr] = v1.w;
        }
        __syncthreads();
#pragma unroll
        for (int k = 0; k < 32; k += 4) {
            float4 q0 = *(const float4*)&bs[k + 0][tx * 4];
            float4 q1 = *(const float4*)&bs[k + 1][tx * 4];
            float4 q2 = *(const float4*)&bs[k + 2][tx * 4];
            float4 q3 = *(const float4*)&bs[k + 3][tx * 4];
#pragma unroll
            for (int i = 0; i < 4; i++) {
                float4 ai = *(const float4*)&as[ty * 4 + i][k];
                acc[i][0] += ai.x * q0.x + ai.y * q1.x + ai.z * q2.x + ai.w * q3.x;
                acc[i][1] += ai.x * q0.y + ai.y * q1.y + ai.z * q2.y + ai.w * q3.y;
                acc[i][2] += ai.x * q0.z + ai.y * q1.z + ai.z * q2.z + ai.w * q3.z;
                acc[i][3] += ai.x * q0.w + ai.y * q1.w + ai.z * q2.w + ai.w * q3.w;
            }
        }
        __syncthreads();
    }
#pragma unroll
    for (int i = 0; i < 4; i++) {
        int r = row0 + ty * 4 + i;
        if (r < M) {
#pragma unroll
            for (int j = 0; j < 4; j++) {
                C[(size_t)r * N + col0 + tx * 4 + j] = acc[i][j];
            }
        }
    }
}

// ---------------- attention scalars: el/er per node per head ----------------
// block = heads*64 threads, one node per block

__global__ void elr_kernel(const float* __restrict__ h, const float* __restrict__ al,
                           const float* __restrict__ ar, float* __restrict__ el,
                           float* __restrict__ er, int heads) {
    int n = blockIdx.x;
    int t = threadIdx.x;
    int lane = t & 63, head = t >> 6;
    float v = h[(size_t)n * blockDim.x + t];
    float a_ = v * al[t];
    float b_ = v * ar[t];
#pragma unroll
    for (int o = 32; o > 0; o >>= 1) {
        a_ += __shfl_xor(a_, o);
        b_ += __shfl_xor(b_, o);
    }
    if (lane == 0) {
        el[n * heads + head] = a_;
        er[n * heads + head] = b_;
    }
}

// ---------------- per-dst-node softmax aggregation ----------------
// one block per dst node; one wave (64 lanes) per head; lane = feature dim

template <int HEADS, bool RELU>
__global__ void agg_kernel(const float* __restrict__ h, const float* __restrict__ el,
                           const float* __restrict__ er, const float* __restrict__ bias,
                           const int* __restrict__ indptr, const int* __restrict__ eidx,
                           const int* __restrict__ srcv, float* __restrict__ out) {
    int d = blockIdx.x;
    int lane = threadIdx.x & 63;
    int head = threadIdx.x >> 6;
    int beg = indptr[d], end = indptr[d + 1];
    int deg = end - beg;

    float acc = 0.f, m = -INFINITY, s = 0.f;
    float erd = er[d * HEADS + head];

    for (int c0 = 0; c0 < deg; c0 += 64) {
        int i = c0 + lane;
        float logit = -INFINITY;
        int sd = 0;
        if (i < deg) {
            int e = eidx[beg + i];
            sd = srcv[e];
            float v = el[sd * HEADS + head] + erd;
            logit = v >= 0.f ? v : NEG_SLOPE * v;
        }
        // wave max of this chunk
        float cm = logit;
#pragma unroll
        for (int o = 32; o > 0; o >>= 1) cm = fmaxf(cm, __shfl_xor(cm, o));
        float mnew = fmaxf(m, cm);
        float r = __expf(m - mnew);  // m=-inf first time -> 0, acc/s are 0 anyway
        acc *= r;
        s *= r;
        m = mnew;
        float p = (i < deg) ? __expf(logit - m) : 0.f;
        float ps = p;
#pragma unroll
        for (int o = 32; o > 0; o >>= 1) ps += __shfl_xor(ps, o);
        s += ps;
        int cnt = min(64, deg - c0);
        for (int j = 0; j < cnt; ++j) {
            float pj = __shfl(p, j);
            int sj = __shfl(sd, j);
            acc += pj * h[(size_t)sj * (HEADS * 64) + head * 64 + lane];
        }
    }
    float o_ = (deg > 0) ? acc / s : 0.f;
    o_ += bias[head * 64 + lane];
    if (RELU) o_ = fmaxf(o_, 0.f);
    out[(size_t)d * (HEADS * 64) + head * 64 + lane] = o_;
}

// ---------------- launch ----------------

extern "C" void kernel_launch(void* const* d_in, const int* in_sizes, int n_in,
                              void* d_out, int out_size, void* d_ws, size_t ws_size,
                              hipStream_t stream) {
    const float* x   = (const float*)d_in[0];
    const int*   src = (const int*)d_in[1];
    const int*   dst = (const int*)d_in[2];
    const float* W0  = (const float*)d_in[3];
    const float* al0 = (const float*)d_in[4];
    const float* ar0 = (const float*)d_in[5];
    const float* b0  = (const float*)d_in[6];
    const float* W1  = (const float*)d_in[7];
    const float* al1 = (const float*)d_in[8];
    const float* ar1 = (const float*)d_in[9];
    const float* b1  = (const float*)d_in[10];
    float* out = (float*)d_out;

    const int N = in_sizes[0] / 256;  // 50000
    const int E = in_sizes[1];        // 800000

    char* ws = (char*)d_ws;
    size_t off = 0;
    auto alloc = [&](size_t bytes) -> void* {
        void* p = ws + off;
        off += (bytes + 255) / 256 * 256;
        return p;
    };
    float* h0      = (float*)alloc((size_t)N * 256 * 4);
    float* el0     = (float*)alloc((size_t)N * 4 * 4);
    float* er0     = (float*)alloc((size_t)N * 4 * 4);
    float* y       = (float*)alloc((size_t)N * 256 * 4);
    float* h1      = (float*)alloc((size_t)N * 64 * 4);
    float* el1     = (float*)alloc((size_t)N * 4);
    float* er1     = (float*)alloc((size_t)N * 4);
    int* counts    = (int*)alloc((size_t)N * 4);
    int* indptr    = (int*)alloc((size_t)(N + 1) * 4);
    int* cursor    = (int*)alloc((size_t)N * 4);
    int* eidx      = (int*)alloc((size_t)E * 4);
    int* blocksums = (int*)alloc(64 * 4);

    // ---- CSR build (by dst) ----
    hipMemsetAsync(counts, 0, (size_t)N * 4, stream);
    count_dst<<<(E + 255) / 256, 256, 0, stream>>>(dst, counts, E);
    int nb = (N + 1023) / 1024;  // 49
    scan_local<<<nb, 256, 0, stream>>>(counts, indptr, blocksums, N);
    scan_carry<<<1, 64, 0, stream>>>(blocksums, nb);
    scan_add<<<nb, 256, 0, stream>>>(indptr, blocksums, N, E);
    hipMemcpyAsync(cursor, indptr, (size_t)N * 4, hipMemcpyDeviceToDevice, stream);
    fill_csr<<<(E + 255) / 256, 256, 0, stream>>>(dst, cursor, eidx, E);

    // ---- layer 0 ----
    dim3 g0((N + 63) / 64, 4);
    gemm_nt<<<g0, 256, 0, stream>>>(x, W0, h0, N, 256, 256);
    elr_kernel<<<N, 256, 0, stream>>>(h0, al0, ar0, el0, er0, 4);
    agg_kernel<4, true><<<N, 256, 0, stream>>>(h0, el0, er0, b0, indptr, eidx, src, y);

    // ---- layer 1 ----
    dim3 g1((N + 63) / 64, 1);
    gemm_nt<<<g1, 256, 0, stream>>>(y, W1, h1, N, 64, 256);
    elr_kernel<<<N, 64, 0, stream>>>(h1, al1, ar1, el1, er1, 1);
    agg_kernel<1, false><<<N, 64, 0, stream>>>(h1, el1, er1, b1, indptr, eidx, src, out);
}

// Round 2
// 471.770 us; speedup vs baseline: 1.2204x; 1.2204x over previous
//
#include <hip/hip_runtime.h>
#include <math.h>

#define NEG_SLOPE 0.2f

// ---------------- CSR build ----------------

__global__ void count_dst(const int* __restrict__ dst, int* __restrict__ counts, int E) {
    int e = blockIdx.x * blockDim.x + threadIdx.x;
    if (e < E) atomicAdd(&counts[dst[e]], 1);
}

// block 256 threads, 1024 elements per block: exclusive scan within block
__global__ void scan_local(const int* __restrict__ counts, int* __restrict__ indptr,
                           int* __restrict__ blocksums, int n) {
    __shared__ int sdata[256];
    int b = blockIdx.x, t = threadIdx.x;
    int base = b * 1024 + t * 4;
    int v[4];
    int sum = 0;
#pragma unroll
    for (int j = 0; j < 4; j++) {
        int idx = base + j;
        v[j] = (idx < n) ? counts[idx] : 0;
        sum += v[j];
    }
    sdata[t] = sum;
    __syncthreads();
    for (int o = 1; o < 256; o <<= 1) {
        int u = 0;
        if (t >= o) u = sdata[t - o];
        __syncthreads();
        if (t >= o) sdata[t] += u;
        __syncthreads();
    }
    int excl = (t > 0) ? sdata[t - 1] : 0;
    int run = excl;
#pragma unroll
    for (int j = 0; j < 4; j++) {
        int idx = base + j;
        if (idx < n) indptr[idx] = run;
        run += v[j];
    }
    if (t == 255) blocksums[b] = sdata[255];
}

__global__ void scan_carry(int* __restrict__ blocksums, int nb) {
    int t = threadIdx.x;  // 64 threads, nb <= 64
    int v = (t < nb) ? blocksums[t] : 0;
    int orig = v;
#pragma unroll
    for (int o = 1; o < 64; o <<= 1) {
        int u = __shfl_up(v, o);
        if (t >= o) v += u;
    }
    if (t < nb) blocksums[t] = v - orig;  // exclusive
}

__global__ void scan_add(int* __restrict__ indptr, const int* __restrict__ blocksums,
                         int n, int Etot) {
    int b = blockIdx.x, t = threadIdx.x;
    int base = b * 1024 + t * 4;
    int add = blocksums[b];
#pragma unroll
    for (int j = 0; j < 4; j++) {
        int idx = base + j;
        if (idx < n) indptr[idx] += add;
    }
    if (b == 0 && t == 0) indptr[n] = Etot;
}

// store the SRC VALUE directly (kills the eidx->src double indirection in agg)
__global__ void fill_csr(const int* __restrict__ dst, const int* __restrict__ src,
                         int* __restrict__ cursor, int* __restrict__ csrc, int E) {
    int e = blockIdx.x * blockDim.x + threadIdx.x;
    if (e < E) {
        int p = atomicAdd(&cursor[dst[e]], 1);
        csrc[p] = src[e];
    }
}

// ---------------- fp32 GEMM: C[M][N] = A[M][K] * B[N][K]^T ----------------
// block 256 threads (16x16), tile 64x64, BK=32, each thread 4x4 micro-tile

__global__ __launch_bounds__(256) void gemm_nt(const float* __restrict__ A,
                                               const float* __restrict__ B,
                                               float* __restrict__ C,
                                               int M, int N, int K) {
    __shared__ float as[64][36];    // [row][k], pad to 36
    __shared__ float bs[32][64];    // [k][col]
    int t = threadIdx.x;
    int tx = t & 15, ty = t >> 4;
    int row0 = blockIdx.x * 64;
    int col0 = blockIdx.y * 64;
    int lr = t >> 2;            // 0..63
    int lk = (t & 3) * 8;       // 0,8,16,24

    float acc[4][4] = {};

    for (int k0 = 0; k0 < K; k0 += 32) {
        {
            int gr = row0 + lr;
            int grc = gr < M ? gr : M - 1;
            const float4* pa = (const float4*)(A + (size_t)grc * K + k0 + lk);
            float4 v0 = pa[0];
            float4 v1 = pa[1];
            *(float4*)&as[lr][lk] = v0;
            *(float4*)&as[lr][lk + 4] = v1;
        }
        {
            const float4* pb = (const float4*)(B + (size_t)(col0 + lr) * K + k0 + lk);
            float4 v0 = pb[0];
            float4 v1 = pb[1];
            bs[lk + 0][lr] = v0.x; bs[lk + 1][lr] = v0.y;
            bs[lk + 2][lr] = v0.z; bs[lk + 3][lr] = v0.w;
            bs[lk + 4][lr] = v1.x; bs[lk + 5][lr] = v1.y;
            bs[lk + 6][lr] = v1.z; bs[lk + 7][lr] = v1.w;
        }
        __syncthreads();
#pragma unroll
        for (int k = 0; k < 32; k += 4) {
            float4 q0 = *(const float4*)&bs[k + 0][tx * 4];
            float4 q1 = *(const float4*)&bs[k + 1][tx * 4];
            float4 q2 = *(const float4*)&bs[k + 2][tx * 4];
            float4 q3 = *(const float4*)&bs[k + 3][tx * 4];
#pragma unroll
            for (int i = 0; i < 4; i++) {
                float4 ai = *(const float4*)&as[ty * 4 + i][k];
                acc[i][0] += ai.x * q0.x + ai.y * q1.x + ai.z * q2.x + ai.w * q3.x;
                acc[i][1] += ai.x * q0.y + ai.y * q1.y + ai.z * q2.y + ai.w * q3.y;
                acc[i][2] += ai.x * q0.z + ai.y * q1.z + ai.z * q2.z + ai.w * q3.z;
                acc[i][3] += ai.x * q0.w + ai.y * q1.w + ai.z * q2.w + ai.w * q3.w;
            }
        }
        __syncthreads();
    }
#pragma unroll
    for (int i = 0; i < 4; i++) {
        int r = row0 + ty * 4 + i;
        if (r < M) {
#pragma unroll
            for (int j = 0; j < 4; j++) {
                C[(size_t)r * N + col0 + tx * 4 + j] = acc[i][j];
            }
        }
    }
}

// ---------------- attention scalars: el/er per node per head ----------------

__global__ void elr_kernel(const float* __restrict__ h, const float* __restrict__ al,
                           const float* __restrict__ ar, float* __restrict__ el,
                           float* __restrict__ er, int heads) {
    int n = blockIdx.x;
    int t = threadIdx.x;
    int lane = t & 63, head = t >> 6;
    float v = h[(size_t)n * blockDim.x + t];
    float a_ = v * al[t];
    float b_ = v * ar[t];
#pragma unroll
    for (int o = 32; o > 0; o >>= 1) {
        a_ += __shfl_xor(a_, o);
        b_ += __shfl_xor(b_, o);
    }
    if (lane == 0) {
        el[n * heads + head] = a_;
        er[n * heads + head] = b_;
    }
}

// ---------------- per-dst-node softmax aggregation ----------------
// 256 threads = 4 waves. HEADS=4: 1 node/block, wave=head.
// HEADS=1: 4 nodes/block, wave=node.
// Within a wave: lane = slot*16 + q. Gather phase processes 4 edges (slots)
// in parallel, each slot reading float4 per lane (16 lanes * 16B = 256B/edge),
// unrolled x2 -> up to 8 independent gathers in flight.

template <int HEADS, bool RELU>
__global__ __launch_bounds__(256) void agg_kernel(
        const float* __restrict__ h, const float* __restrict__ el,
        const float* __restrict__ er, const float* __restrict__ bias,
        const int* __restrict__ indptr, const int* __restrict__ csrc,
        float* __restrict__ out, int N) {
    int t = threadIdx.x;
    int wave = t >> 6;
    int lane = t & 63;
    int slot = lane >> 4;
    int q = lane & 15;
    int node = blockIdx.x * (4 / HEADS) + wave / HEADS;
    int head = wave % HEADS;
    if (node >= N) return;

    int beg = indptr[node], end = indptr[node + 1];
    int deg = end - beg;

    float4 acc = {0.f, 0.f, 0.f, 0.f};
    float m = -INFINITY, s = 0.f;
    float erd = er[node * HEADS + head];

    for (int c0 = 0; c0 < deg; c0 += 64) {
        int i = c0 + lane;
        float logit = -INFINITY;
        int sd = 0;
        if (i < deg) {
            sd = csrc[beg + i];
            float v = el[sd * HEADS + head] + erd;
            logit = v >= 0.f ? v : NEG_SLOPE * v;
        }
        float cm = logit;
#pragma unroll
        for (int o = 32; o > 0; o >>= 1) cm = fmaxf(cm, __shfl_xor(cm, o));
        float mnew = fmaxf(m, cm);
        float r = __expf(m - mnew);  // first chunk: exp(-inf)=0, acc/s already 0
        acc.x *= r; acc.y *= r; acc.z *= r; acc.w *= r;
        s *= r;
        m = mnew;
        float p = (i < deg) ? __expf(logit - m) : 0.f;
        float ps = p;
#pragma unroll
        for (int o = 32; o > 0; o >>= 1) ps += __shfl_xor(ps, o);
        s += ps;
        int cnt = min(64, deg - c0);
        for (int j = 0; j < cnt; j += 8) {
            int j0 = j + slot;
            int j1 = j + 4 + slot;
            float p0 = __shfl(p, j0);
            int sd0 = __shfl(sd, j0);
            float p1 = __shfl(p, j1);
            int sd1 = __shfl(sd, j1);
            if (j0 < cnt) {
                float4 hv = *(const float4*)&h[(size_t)sd0 * (HEADS * 64) + head * 64 + q * 4];
                acc.x += p0 * hv.x; acc.y += p0 * hv.y;
                acc.z += p0 * hv.z; acc.w += p0 * hv.w;
            }
            if (j1 < cnt) {
                float4 hv = *(const float4*)&h[(size_t)sd1 * (HEADS * 64) + head * 64 + q * 4];
                acc.x += p1 * hv.x; acc.y += p1 * hv.y;
                acc.z += p1 * hv.z; acc.w += p1 * hv.w;
            }
        }
    }
    // reduce the 4 edge-slots (lanes differing in bits 4,5)
#pragma unroll
    for (int o = 16; o <= 32; o <<= 1) {
        acc.x += __shfl_xor(acc.x, o);
        acc.y += __shfl_xor(acc.y, o);
        acc.z += __shfl_xor(acc.z, o);
        acc.w += __shfl_xor(acc.w, o);
    }
    if (slot == 0) {
        float inv = (deg > 0) ? 1.f / s : 0.f;
        const float4 b4 = *(const float4*)&bias[head * 64 + q * 4];
        float4 o4;
        o4.x = acc.x * inv + b4.x;
        o4.y = acc.y * inv + b4.y;
        o4.z = acc.z * inv + b4.z;
        o4.w = acc.w * inv + b4.w;
        if (RELU) {
            o4.x = fmaxf(o4.x, 0.f); o4.y = fmaxf(o4.y, 0.f);
            o4.z = fmaxf(o4.z, 0.f); o4.w = fmaxf(o4.w, 0.f);
        }
        *(float4*)&out[(size_t)node * (HEADS * 64) + head * 64 + q * 4] = o4;
    }
}

// ---------------- launch ----------------

extern "C" void kernel_launch(void* const* d_in, const int* in_sizes, int n_in,
                              void* d_out, int out_size, void* d_ws, size_t ws_size,
                              hipStream_t stream) {
    const float* x   = (const float*)d_in[0];
    const int*   src = (const int*)d_in[1];
    const int*   dst = (const int*)d_in[2];
    const float* W0  = (const float*)d_in[3];
    const float* al0 = (const float*)d_in[4];
    const float* ar0 = (const float*)d_in[5];
    const float* b0  = (const float*)d_in[6];
    const float* W1  = (const float*)d_in[7];
    const float* al1 = (const float*)d_in[8];
    const float* ar1 = (const float*)d_in[9];
    const float* b1  = (const float*)d_in[10];
    float* out = (float*)d_out;

    const int N = in_sizes[0] / 256;  // 50000
    const int E = in_sizes[1];        // 800000

    char* ws = (char*)d_ws;
    size_t off = 0;
    auto alloc = [&](size_t bytes) -> void* {
        void* p = ws + off;
        off += (bytes + 255) / 256 * 256;
        return p;
    };
    float* h0      = (float*)alloc((size_t)N * 256 * 4);
    float* el0     = (float*)alloc((size_t)N * 4 * 4);
    float* er0     = (float*)alloc((size_t)N * 4 * 4);
    float* y       = (float*)alloc((size_t)N * 256 * 4);
    float* h1      = (float*)alloc((size_t)N * 64 * 4);
    float* el1     = (float*)alloc((size_t)N * 4);
    float* er1     = (float*)alloc((size_t)N * 4);
    int* counts    = (int*)alloc((size_t)N * 4);
    int* indptr    = (int*)alloc((size_t)(N + 1) * 4);
    int* cursor    = (int*)alloc((size_t)N * 4);
    int* csrc      = (int*)alloc((size_t)E * 4);
    int* blocksums = (int*)alloc(64 * 4);

    // ---- CSR build (by dst) ----
    hipMemsetAsync(counts, 0, (size_t)N * 4, stream);
    count_dst<<<(E + 255) / 256, 256, 0, stream>>>(dst, counts, E);
    int nb = (N + 1023) / 1024;  // 49
    scan_local<<<nb, 256, 0, stream>>>(counts, indptr, blocksums, N);
    scan_carry<<<1, 64, 0, stream>>>(blocksums, nb);
    scan_add<<<nb, 256, 0, stream>>>(indptr, blocksums, N, E);
    hipMemcpyAsync(cursor, indptr, (size_t)N * 4, hipMemcpyDeviceToDevice, stream);
    fill_csr<<<(E + 255) / 256, 256, 0, stream>>>(dst, src, cursor, csrc, E);

    // ---- layer 0 ----
    dim3 g0((N + 63) / 64, 4);
    gemm_nt<<<g0, 256, 0, stream>>>(x, W0, h0, N, 256, 256);
    elr_kernel<<<N, 256, 0, stream>>>(h0, al0, ar0, el0, er0, 4);
    agg_kernel<4, true><<<N, 256, 0, stream>>>(h0, el0, er0, b0, indptr, csrc, y, N);

    // ---- layer 1 ----
    dim3 g1((N + 63) / 64, 1);
    gemm_nt<<<g1, 256, 0, stream>>>(y, W1, h1, N, 64, 256);
    elr_kernel<<<N, 64, 0, stream>>>(h1, al1, ar1, el1, er1, 1);
    agg_kernel<1, false><<<(N + 3) / 4, 256, 0, stream>>>(h1, el1, er1, b1, indptr, csrc, out, N);
}

// Round 3
// 350.299 us; speedup vs baseline: 1.6436x; 1.3468x over previous
//
#include <hip/hip_runtime.h>
#include <math.h>

#define NEG_SLOPE 0.2f

using f16   = _Float16;
using f16x8 = __attribute__((ext_vector_type(8))) _Float16;
using f32x4 = __attribute__((ext_vector_type(4))) float;

// ---------------- CSR build ----------------

__global__ void count_dst(const int* __restrict__ dst, int* __restrict__ counts, int E) {
    int e = blockIdx.x * blockDim.x + threadIdx.x;
    if (e < E) atomicAdd(&counts[dst[e]], 1);
}

__global__ void scan_local(const int* __restrict__ counts, int* __restrict__ indptr,
                           int* __restrict__ blocksums, int n) {
    __shared__ int sdata[256];
    int b = blockIdx.x, t = threadIdx.x;
    int base = b * 1024 + t * 4;
    int v[4];
    int sum = 0;
#pragma unroll
    for (int j = 0; j < 4; j++) {
        int idx = base + j;
        v[j] = (idx < n) ? counts[idx] : 0;
        sum += v[j];
    }
    sdata[t] = sum;
    __syncthreads();
    for (int o = 1; o < 256; o <<= 1) {
        int u = 0;
        if (t >= o) u = sdata[t - o];
        __syncthreads();
        if (t >= o) sdata[t] += u;
        __syncthreads();
    }
    int excl = (t > 0) ? sdata[t - 1] : 0;
    int run = excl;
#pragma unroll
    for (int j = 0; j < 4; j++) {
        int idx = base + j;
        if (idx < n) indptr[idx] = run;
        run += v[j];
    }
    if (t == 255) blocksums[b] = sdata[255];
}

__global__ void scan_carry(int* __restrict__ blocksums, int nb) {
    int t = threadIdx.x;
    int v = (t < nb) ? blocksums[t] : 0;
    int orig = v;
#pragma unroll
    for (int o = 1; o < 64; o <<= 1) {
        int u = __shfl_up(v, o);
        if (t >= o) v += u;
    }
    if (t < nb) blocksums[t] = v - orig;
}

__global__ void scan_add(int* __restrict__ indptr, const int* __restrict__ blocksums,
                         int n, int Etot) {
    int b = blockIdx.x, t = threadIdx.x;
    int base = b * 1024 + t * 4;
    int add = blocksums[b];
#pragma unroll
    for (int j = 0; j < 4; j++) {
        int idx = base + j;
        if (idx < n) indptr[idx] += add;
    }
    if (b == 0 && t == 0) indptr[n] = Etot;
}

__global__ void fill_csr(const int* __restrict__ dst, const int* __restrict__ src,
                         int* __restrict__ cursor, int* __restrict__ csrc, int E) {
    int e = blockIdx.x * blockDim.x + threadIdx.x;
    if (e < E) {
        int p = atomicAdd(&cursor[dst[e]], 1);
        csrc[p] = src[e];
    }
}

// ---------------- f16-MFMA GEMM: C[M][BN] = A[M][256] * B[BN][256]^T ----------------
// BM=64, BK=32, K=256 fixed. 256 threads = 4 waves.
// BN=256: waves side-by-side in N (wave tile 64x64, 4x4 frags).
// BN=64:  waves stacked in M (wave tile 16x64, 1x4 frags).
// fp32 loaded from global, converted to f16 into padded LDS (40 f16 = 80B rows,
// 16B-aligned, banks spread -> ~2-way max, free on wave64).

template <int BN>
__global__ __launch_bounds__(256) void gemm_mfma(const float* __restrict__ A,
                                                 const float* __restrict__ B,
                                                 float* __restrict__ C, int M) {
    constexpr int K = 256;
    constexpr int WAVES_N = BN / 64;       // 4 or 1
    constexpr int WAVES_M = 4 / WAVES_N;   // 1 or 4
    constexpr int WM = 64 / WAVES_M;       // 64 or 16
    constexpr int MF = WM / 16;            // 4 or 1

    __shared__ f16 as[64][40];
    __shared__ f16 bs[BN][40];

    int t = threadIdx.x;
    int wave = t >> 6, lane = t & 63;
    int wn = wave / WAVES_M;               // 0..WAVES_N-1
    int wm = wave % WAVES_M;               // 0..WAVES_M-1
    int row0 = blockIdx.x * 64;

    int srow = t >> 2;                     // 0..63
    int skq = (t & 3) * 8;                 // 0,8,16,24

    int lrow = lane & 15;
    int ksel = (lane >> 4) * 8;            // k-subblock within BK=32

    f32x4 acc[MF][4] = {};

    for (int k0 = 0; k0 < K; k0 += 32) {
        // stage A (64 x 32), fp32 -> f16
        {
            int gr = row0 + srow;
            gr = gr < M ? gr : M - 1;
            const float4* pa = (const float4*)(A + (size_t)gr * K + k0 + skq);
            float4 u0 = pa[0], u1 = pa[1];
            f16x8 av;
            av[0] = (f16)u0.x; av[1] = (f16)u0.y; av[2] = (f16)u0.z; av[3] = (f16)u0.w;
            av[4] = (f16)u1.x; av[5] = (f16)u1.y; av[6] = (f16)u1.z; av[7] = (f16)u1.w;
            *(f16x8*)&as[srow][skq] = av;
        }
        // stage B (BN x 32), fp32 -> f16
#pragma unroll
        for (int i = 0; i < BN / 64; i++) {
            int n = i * 64 + srow;
            const float4* pb = (const float4*)(B + (size_t)n * K + k0 + skq);
            float4 u0 = pb[0], u1 = pb[1];
            f16x8 bv;
            bv[0] = (f16)u0.x; bv[1] = (f16)u0.y; bv[2] = (f16)u0.z; bv[3] = (f16)u0.w;
            bv[4] = (f16)u1.x; bv[5] = (f16)u1.y; bv[6] = (f16)u1.z; bv[7] = (f16)u1.w;
            *(f16x8*)&bs[n][skq] = bv;
        }
        __syncthreads();

        f16x8 af[MF], bf[4];
#pragma unroll
        for (int i = 0; i < MF; i++)
            af[i] = *(const f16x8*)&as[wm * WM + i * 16 + lrow][ksel];
#pragma unroll
        for (int j = 0; j < 4; j++)
            bf[j] = *(const f16x8*)&bs[wn * 64 + j * 16 + lrow][ksel];
#pragma unroll
        for (int i = 0; i < MF; i++)
#pragma unroll
            for (int j = 0; j < 4; j++)
                acc[i][j] = __builtin_amdgcn_mfma_f32_16x16x32_f16(af[i], bf[j], acc[i][j], 0, 0, 0);
        __syncthreads();
    }

    // epilogue: D row = (lane>>4)*4 + reg, col = lane&15
#pragma unroll
    for (int i = 0; i < MF; i++) {
        int r0 = row0 + wm * WM + i * 16 + (lane >> 4) * 4;
#pragma unroll
        for (int j = 0; j < 4; j++) {
            int col = wn * 64 + j * 16 + (lane & 15);
#pragma unroll
            for (int r = 0; r < 4; r++) {
                int gr = r0 + r;
                if (gr < M) C[(size_t)gr * BN + col] = acc[i][j][r];
            }
        }
    }
}

// ---------------- attention scalars: el/er per node per head ----------------

__global__ void elr_kernel(const float* __restrict__ h, const float* __restrict__ al,
                           const float* __restrict__ ar, float* __restrict__ el,
                           float* __restrict__ er, int heads) {
    int n = blockIdx.x;
    int t = threadIdx.x;
    int lane = t & 63, head = t >> 6;
    float v = h[(size_t)n * blockDim.x + t];
    float a_ = v * al[t];
    float b_ = v * ar[t];
#pragma unroll
    for (int o = 32; o > 0; o >>= 1) {
        a_ += __shfl_xor(a_, o);
        b_ += __shfl_xor(b_, o);
    }
    if (lane == 0) {
        el[n * heads + head] = a_;
        er[n * heads + head] = b_;
    }
}

// ---------------- per-dst-node softmax aggregation ----------------

template <int HEADS, bool RELU>
__global__ __launch_bounds__(256) void agg_kernel(
        const float* __restrict__ h, const float* __restrict__ el,
        const float* __restrict__ er, const float* __restrict__ bias,
        const int* __restrict__ indptr, const int* __restrict__ csrc,
        float* __restrict__ out, int N) {
    int t = threadIdx.x;
    int wave = t >> 6;
    int lane = t & 63;
    int slot = lane >> 4;
    int q = lane & 15;
    int node = blockIdx.x * (4 / HEADS) + wave / HEADS;
    int head = wave % HEADS;
    if (node >= N) return;

    int beg = indptr[node], end = indptr[node + 1];
    int deg = end - beg;

    float4 acc = {0.f, 0.f, 0.f, 0.f};
    float m = -INFINITY, s = 0.f;
    float erd = er[node * HEADS + head];

    for (int c0 = 0; c0 < deg; c0 += 64) {
        int i = c0 + lane;
        float logit = -INFINITY;
        int sd = 0;
        if (i < deg) {
            sd = csrc[beg + i];
            float v = el[sd * HEADS + head] + erd;
            logit = v >= 0.f ? v : NEG_SLOPE * v;
        }
        float cm = logit;
#pragma unroll
        for (int o = 32; o > 0; o >>= 1) cm = fmaxf(cm, __shfl_xor(cm, o));
        float mnew = fmaxf(m, cm);
        float r = __expf(m - mnew);
        acc.x *= r; acc.y *= r; acc.z *= r; acc.w *= r;
        s *= r;
        m = mnew;
        float p = (i < deg) ? __expf(logit - m) : 0.f;
        float ps = p;
#pragma unroll
        for (int o = 32; o > 0; o >>= 1) ps += __shfl_xor(ps, o);
        s += ps;
        int cnt = min(64, deg - c0);
        for (int j = 0; j < cnt; j += 8) {
            int j0 = j + slot;
            int j1 = j + 4 + slot;
            float p0 = __shfl(p, j0);
            int sd0 = __shfl(sd, j0);
            float p1 = __shfl(p, j1);
            int sd1 = __shfl(sd, j1);
            if (j0 < cnt) {
                float4 hv = *(const float4*)&h[(size_t)sd0 * (HEADS * 64) + head * 64 + q * 4];
                acc.x += p0 * hv.x; acc.y += p0 * hv.y;
                acc.z += p0 * hv.z; acc.w += p0 * hv.w;
            }
            if (j1 < cnt) {
                float4 hv = *(const float4*)&h[(size_t)sd1 * (HEADS * 64) + head * 64 + q * 4];
                acc.x += p1 * hv.x; acc.y += p1 * hv.y;
                acc.z += p1 * hv.z; acc.w += p1 * hv.w;
            }
        }
    }
#pragma unroll
    for (int o = 16; o <= 32; o <<= 1) {
        acc.x += __shfl_xor(acc.x, o);
        acc.y += __shfl_xor(acc.y, o);
        acc.z += __shfl_xor(acc.z, o);
        acc.w += __shfl_xor(acc.w, o);
    }
    if (slot == 0) {
        float inv = (deg > 0) ? 1.f / s : 0.f;
        const float4 b4 = *(const float4*)&bias[head * 64 + q * 4];
        float4 o4;
        o4.x = acc.x * inv + b4.x;
        o4.y = acc.y * inv + b4.y;
        o4.z = acc.z * inv + b4.z;
        o4.w = acc.w * inv + b4.w;
        if (RELU) {
            o4.x = fmaxf(o4.x, 0.f); o4.y = fmaxf(o4.y, 0.f);
            o4.z = fmaxf(o4.z, 0.f); o4.w = fmaxf(o4.w, 0.f);
        }
        *(float4*)&out[(size_t)node * (HEADS * 64) + head * 64 + q * 4] = o4;
    }
}

// ---------------- launch ----------------

extern "C" void kernel_launch(void* const* d_in, const int* in_sizes, int n_in,
                              void* d_out, int out_size, void* d_ws, size_t ws_size,
                              hipStream_t stream) {
    const float* x   = (const float*)d_in[0];
    const int*   src = (const int*)d_in[1];
    const int*   dst = (const int*)d_in[2];
    const float* W0  = (const float*)d_in[3];
    const float* al0 = (const float*)d_in[4];
    const float* ar0 = (const float*)d_in[5];
    const float* b0  = (const float*)d_in[6];
    const float* W1  = (const float*)d_in[7];
    const float* al1 = (const float*)d_in[8];
    const float* ar1 = (const float*)d_in[9];
    const float* b1  = (const float*)d_in[10];
    float* out = (float*)d_out;

    const int N = in_sizes[0] / 256;  // 50000
    const int E = in_sizes[1];        // 800000

    char* ws = (char*)d_ws;
    size_t off = 0;
    auto alloc = [&](size_t bytes) -> void* {
        void* p = ws + off;
        off += (bytes + 255) / 256 * 256;
        return p;
    };
    float* h0      = (float*)alloc((size_t)N * 256 * 4);
    float* el0     = (float*)alloc((size_t)N * 4 * 4);
    float* er0     = (float*)alloc((size_t)N * 4 * 4);
    float* y       = (float*)alloc((size_t)N * 256 * 4);
    float* h1      = (float*)alloc((size_t)N * 64 * 4);
    float* el1     = (float*)alloc((size_t)N * 4);
    float* er1     = (float*)alloc((size_t)N * 4);
    int* counts    = (int*)alloc((size_t)N * 4);
    int* indptr    = (int*)alloc((size_t)(N + 1) * 4);
    int* cursor    = (int*)alloc((size_t)N * 4);
    int* csrc      = (int*)alloc((size_t)E * 4);
    int* blocksums = (int*)alloc(64 * 4);

    // ---- CSR build (by dst) ----
    hipMemsetAsync(counts, 0, (size_t)N * 4, stream);
    count_dst<<<(E + 255) / 256, 256, 0, stream>>>(dst, counts, E);
    int nb = (N + 1023) / 1024;  // 49
    scan_local<<<nb, 256, 0, stream>>>(counts, indptr, blocksums, N);
    scan_carry<<<1, 64, 0, stream>>>(blocksums, nb);
    scan_add<<<nb, 256, 0, stream>>>(indptr, blocksums, N, E);
    hipMemcpyAsync(cursor, indptr, (size_t)N * 4, hipMemcpyDeviceToDevice, stream);
    fill_csr<<<(E + 255) / 256, 256, 0, stream>>>(dst, src, cursor, csrc, E);

    // ---- layer 0 ----
    int mtiles = (N + 63) / 64;  // 782
    gemm_mfma<256><<<mtiles, 256, 0, stream>>>(x, W0, h0, N);
    elr_kernel<<<N, 256, 0, stream>>>(h0, al0, ar0, el0, er0, 4);
    agg_kernel<4, true><<<N, 256, 0, stream>>>(h0, el0, er0, b0, indptr, csrc, y, N);

    // ---- layer 1 ----
    gemm_mfma<64><<<mtiles, 256, 0, stream>>>(y, W1, h1, N);
    elr_kernel<<<N, 64, 0, stream>>>(h1, al1, ar1, el1, er1, 1);
    agg_kernel<1, false><<<(N + 3) / 4, 256, 0, stream>>>(h1, el1, er1, b1, indptr, csrc, out, N);
}

// Round 4
// 288.891 us; speedup vs baseline: 1.9930x; 1.2126x over previous
//
#include <hip/hip_runtime.h>
#include <math.h>

#define NEG_SLOPE 0.2f

using f16   = _Float16;
using f16x4 = __attribute__((ext_vector_type(4))) _Float16;
using f16x8 = __attribute__((ext_vector_type(8))) _Float16;
using f32x4 = __attribute__((ext_vector_type(4))) float;

// ---------------- CSR build ----------------

__global__ void count_dst(const int* __restrict__ dst, int* __restrict__ counts, int E) {
    int e = blockIdx.x * blockDim.x + threadIdx.x;
    if (e < E) atomicAdd(&counts[dst[e]], 1);
}

__global__ void scan_local(const int* __restrict__ counts, int* __restrict__ indptr,
                           int* __restrict__ blocksums, int n) {
    __shared__ int sdata[256];
    int b = blockIdx.x, t = threadIdx.x;
    int base = b * 1024 + t * 4;
    int v[4];
    int sum = 0;
#pragma unroll
    for (int j = 0; j < 4; j++) {
        int idx = base + j;
        v[j] = (idx < n) ? counts[idx] : 0;
        sum += v[j];
    }
    sdata[t] = sum;
    __syncthreads();
    for (int o = 1; o < 256; o <<= 1) {
        int u = 0;
        if (t >= o) u = sdata[t - o];
        __syncthreads();
        if (t >= o) sdata[t] += u;
        __syncthreads();
    }
    int excl = (t > 0) ? sdata[t - 1] : 0;
    int run = excl;
#pragma unroll
    for (int j = 0; j < 4; j++) {
        int idx = base + j;
        if (idx < n) indptr[idx] = run;
        run += v[j];
    }
    if (t == 255) blocksums[b] = sdata[255];
}

__global__ void scan_carry(int* __restrict__ blocksums, int nb) {
    int t = threadIdx.x;
    int v = (t < nb) ? blocksums[t] : 0;
    int orig = v;
#pragma unroll
    for (int o = 1; o < 64; o <<= 1) {
        int u = __shfl_up(v, o);
        if (t >= o) v += u;
    }
    if (t < nb) blocksums[t] = v - orig;
}

__global__ void scan_add(int* __restrict__ indptr, const int* __restrict__ blocksums,
                         int n, int Etot) {
    int b = blockIdx.x, t = threadIdx.x;
    int base = b * 1024 + t * 4;
    int add = blocksums[b];
#pragma unroll
    for (int j = 0; j < 4; j++) {
        int idx = base + j;
        if (idx < n) indptr[idx] += add;
    }
    if (b == 0 && t == 0) indptr[n] = Etot;
}

__global__ void fill_csr(const int* __restrict__ dst, const int* __restrict__ src,
                         int* __restrict__ cursor, int* __restrict__ csrc, int E) {
    int e = blockIdx.x * blockDim.x + threadIdx.x;
    if (e < E) {
        int p = atomicAdd(&cursor[dst[e]], 1);
        csrc[p] = src[e];
    }
}

// ---------------- f16-MFMA GEMM: C[M][BN] = A[M][256] * B[BN][256]^T, C in f16 ----
// BM=64, BK=32, K=256 fixed. 256 threads = 4 waves.
// TA = float (convert at stage) or f16 (direct copy).

template <int BN, typename TA>
__global__ __launch_bounds__(256) void gemm_mfma(const TA* __restrict__ A,
                                                 const float* __restrict__ B,
                                                 f16* __restrict__ C, int M) {
    constexpr int K = 256;
    constexpr int WAVES_N = BN / 64;
    constexpr int WAVES_M = 4 / WAVES_N;
    constexpr int WM = 64 / WAVES_M;
    constexpr int MF = WM / 16;

    __shared__ f16 as[64][40];
    __shared__ f16 bs[BN][40];

    int t = threadIdx.x;
    int wave = t >> 6, lane = t & 63;
    int wn = wave / WAVES_M;
    int wm = wave % WAVES_M;
    int row0 = blockIdx.x * 64;

    int srow = t >> 2;       // 0..63
    int skq = (t & 3) * 8;   // 0,8,16,24

    int lrow = lane & 15;
    int ksel = (lane >> 4) * 8;

    f32x4 acc[MF][4] = {};

    for (int k0 = 0; k0 < K; k0 += 32) {
        {
            int gr = row0 + srow;
            gr = gr < M ? gr : M - 1;
            if constexpr (sizeof(TA) == 4) {
                const float4* pa = (const float4*)(A + (size_t)gr * K + k0 + skq);
                float4 u0 = pa[0], u1 = pa[1];
                f16x8 av;
                av[0] = (f16)u0.x; av[1] = (f16)u0.y; av[2] = (f16)u0.z; av[3] = (f16)u0.w;
                av[4] = (f16)u1.x; av[5] = (f16)u1.y; av[6] = (f16)u1.z; av[7] = (f16)u1.w;
                *(f16x8*)&as[srow][skq] = av;
            } else {
                *(f16x8*)&as[srow][skq] = *(const f16x8*)(A + (size_t)gr * K + k0 + skq);
            }
        }
#pragma unroll
        for (int i = 0; i < BN / 64; i++) {
            int n = i * 64 + srow;
            const float4* pb = (const float4*)(B + (size_t)n * K + k0 + skq);
            float4 u0 = pb[0], u1 = pb[1];
            f16x8 bv;
            bv[0] = (f16)u0.x; bv[1] = (f16)u0.y; bv[2] = (f16)u0.z; bv[3] = (f16)u0.w;
            bv[4] = (f16)u1.x; bv[5] = (f16)u1.y; bv[6] = (f16)u1.z; bv[7] = (f16)u1.w;
            *(f16x8*)&bs[n][skq] = bv;
        }
        __syncthreads();

        f16x8 af[MF], bf[4];
#pragma unroll
        for (int i = 0; i < MF; i++)
            af[i] = *(const f16x8*)&as[wm * WM + i * 16 + lrow][ksel];
#pragma unroll
        for (int j = 0; j < 4; j++)
            bf[j] = *(const f16x8*)&bs[wn * 64 + j * 16 + lrow][ksel];
#pragma unroll
        for (int i = 0; i < MF; i++)
#pragma unroll
            for (int j = 0; j < 4; j++)
                acc[i][j] = __builtin_amdgcn_mfma_f32_16x16x32_f16(af[i], bf[j], acc[i][j], 0, 0, 0);
        __syncthreads();
    }

#pragma unroll
    for (int i = 0; i < MF; i++) {
        int r0 = row0 + wm * WM + i * 16 + (lane >> 4) * 4;
#pragma unroll
        for (int j = 0; j < 4; j++) {
            int col = wn * 64 + j * 16 + (lane & 15);
#pragma unroll
            for (int r = 0; r < 4; r++) {
                int gr = r0 + r;
                if (gr < M) C[(size_t)gr * BN + col] = (f16)acc[i][j][r];
            }
        }
    }
}

// ---------------- attention scalars: el/er per node per head ----------------
// f16x4 per lane; 16-lane groups reduce one head of one node.

template <int HEADS>
__global__ __launch_bounds__(256) void elr_kernel(const f16* __restrict__ h,
                                                  const float* __restrict__ al,
                                                  const float* __restrict__ ar,
                                                  float* __restrict__ el,
                                                  float* __restrict__ er, int N) {
    constexpr int F = HEADS * 64;
    constexpr int LPN = HEADS * 16;   // lanes per node
    constexpr int NPW = 64 / LPN;     // nodes per wave
    int t = threadIdx.x;
    int wave = t >> 6, lane = t & 63;
    int node = (blockIdx.x * 4 + wave) * NPW + lane / LPN;
    int fl = lane % LPN;
    int feat = fl * 4;
    int head = feat >> 6;
    if (node >= N) return;
    f16x4 hv = *(const f16x4*)&h[(size_t)node * F + feat];
    float4 av = *(const float4*)&al[feat];
    float4 rv = *(const float4*)&ar[feat];
    float a_ = (float)hv[0] * av.x + (float)hv[1] * av.y + (float)hv[2] * av.z + (float)hv[3] * av.w;
    float b_ = (float)hv[0] * rv.x + (float)hv[1] * rv.y + (float)hv[2] * rv.z + (float)hv[3] * rv.w;
#pragma unroll
    for (int o = 1; o <= 8; o <<= 1) {
        a_ += __shfl_xor(a_, o);
        b_ += __shfl_xor(b_, o);
    }
    if ((lane & 15) == 0) {
        el[node * HEADS + head] = a_;
        er[node * HEADS + head] = b_;
    }
}

// ---------------- per-dst-node softmax aggregation (f16 gather table) ------
// wave = one (node, head). lane = slot*8 + q: 8 edge-slots x 8 lanes x f16x8
// (16B) = 128B per edge row; x2 unroll -> 16 gathers in flight per wave.

template <int HEADS, bool RELU, typename TOUT>
__global__ __launch_bounds__(256) void agg_kernel(
        const f16* __restrict__ h, const float* __restrict__ el,
        const float* __restrict__ er, const float* __restrict__ bias,
        const int* __restrict__ indptr, const int* __restrict__ csrc,
        TOUT* __restrict__ out, int N) {
    int t = threadIdx.x;
    int wave = t >> 6, lane = t & 63;
    int slot = lane >> 3, q = lane & 7;
    int node = blockIdx.x * (4 / HEADS) + wave / HEADS;
    int head = wave % HEADS;
    if (node >= N) return;

    int beg = indptr[node], end = indptr[node + 1];
    int deg = end - beg;

    float a[8] = {};
    float m = -INFINITY, s = 0.f;
    float erd = er[node * HEADS + head];

    for (int c0 = 0; c0 < deg; c0 += 64) {
        int i = c0 + lane;
        float logit = -INFINITY;
        int sd = 0;
        if (i < deg) {
            sd = csrc[beg + i];
            float v = el[sd * HEADS + head] + erd;
            logit = v >= 0.f ? v : NEG_SLOPE * v;
        }
        float cm = logit;
#pragma unroll
        for (int o = 32; o > 0; o >>= 1) cm = fmaxf(cm, __shfl_xor(cm, o));
        float mnew = fmaxf(m, cm);
        float r = __expf(m - mnew);
#pragma unroll
        for (int k = 0; k < 8; k++) a[k] *= r;
        s *= r;
        m = mnew;
        float p = (i < deg) ? __expf(logit - m) : 0.f;
        float ps = p;
#pragma unroll
        for (int o = 32; o > 0; o >>= 1) ps += __shfl_xor(ps, o);
        s += ps;
        int cnt = min(64, deg - c0);
        for (int j = 0; j < cnt; j += 16) {
            int j0 = j + slot;
            int j1 = j + 8 + slot;
            float p0 = __shfl(p, j0);
            int sd0 = __shfl(sd, j0);
            float p1 = __shfl(p, j1);
            int sd1 = __shfl(sd, j1);
            if (j0 < cnt) {
                f16x8 hv = *(const f16x8*)&h[((size_t)sd0 * HEADS + head) * 64 + q * 8];
#pragma unroll
                for (int k = 0; k < 8; k++) a[k] += p0 * (float)hv[k];
            }
            if (j1 < cnt) {
                f16x8 hv = *(const f16x8*)&h[((size_t)sd1 * HEADS + head) * 64 + q * 8];
#pragma unroll
                for (int k = 0; k < 8; k++) a[k] += p1 * (float)hv[k];
            }
        }
    }
    // reduce 8 edge-slots (lane bits 3,4,5)
#pragma unroll
    for (int o = 8; o <= 32; o <<= 1) {
#pragma unroll
        for (int k = 0; k < 8; k++) a[k] += __shfl_xor(a[k], o);
    }
    if (slot == 0) {
        float inv = (deg > 0) ? 1.f / s : 0.f;
        const float4 b0 = *(const float4*)&bias[head * 64 + q * 8];
        const float4 b1 = *(const float4*)&bias[head * 64 + q * 8 + 4];
        float v[8];
        v[0] = a[0] * inv + b0.x; v[1] = a[1] * inv + b0.y;
        v[2] = a[2] * inv + b0.z; v[3] = a[3] * inv + b0.w;
        v[4] = a[4] * inv + b1.x; v[5] = a[5] * inv + b1.y;
        v[6] = a[6] * inv + b1.z; v[7] = a[7] * inv + b1.w;
        if (RELU) {
#pragma unroll
            for (int k = 0; k < 8; k++) v[k] = fmaxf(v[k], 0.f);
        }
        size_t o_off = (size_t)node * (HEADS * 64) + head * 64 + q * 8;
        if constexpr (sizeof(TOUT) == 2) {
            f16x8 o8;
#pragma unroll
            for (int k = 0; k < 8; k++) o8[k] = (f16)v[k];
            *(f16x8*)&out[o_off] = o8;
        } else {
            float4 oa = {v[0], v[1], v[2], v[3]};
            float4 ob = {v[4], v[5], v[6], v[7]};
            *(float4*)&out[o_off] = oa;
            *(float4*)&out[o_off + 4] = ob;
        }
    }
}

// ---------------- launch ----------------

extern "C" void kernel_launch(void* const* d_in, const int* in_sizes, int n_in,
                              void* d_out, int out_size, void* d_ws, size_t ws_size,
                              hipStream_t stream) {
    const float* x   = (const float*)d_in[0];
    const int*   src = (const int*)d_in[1];
    const int*   dst = (const int*)d_in[2];
    const float* W0  = (const float*)d_in[3];
    const float* al0 = (const float*)d_in[4];
    const float* ar0 = (const float*)d_in[5];
    const float* b0  = (const float*)d_in[6];
    const float* W1  = (const float*)d_in[7];
    const float* al1 = (const float*)d_in[8];
    const float* ar1 = (const float*)d_in[9];
    const float* b1  = (const float*)d_in[10];
    float* out = (float*)d_out;

    const int N = in_sizes[0] / 256;  // 50000
    const int E = in_sizes[1];        // 800000

    char* ws = (char*)d_ws;
    size_t off = 0;
    auto alloc = [&](size_t bytes) -> void* {
        void* p = ws + off;
        off += (bytes + 255) / 256 * 256;
        return p;
    };
    f16* h0        = (f16*)alloc((size_t)N * 256 * 2);
    f16* y         = (f16*)alloc((size_t)N * 256 * 2);
    f16* h1        = (f16*)alloc((size_t)N * 64 * 2);
    float* el0     = (float*)alloc((size_t)N * 4 * 4);
    float* er0     = (float*)alloc((size_t)N * 4 * 4);
    float* el1     = (float*)alloc((size_t)N * 4);
    float* er1     = (float*)alloc((size_t)N * 4);
    int* counts    = (int*)alloc((size_t)N * 4);
    int* indptr    = (int*)alloc((size_t)(N + 1) * 4);
    int* cursor    = (int*)alloc((size_t)N * 4);
    int* csrc      = (int*)alloc((size_t)E * 4);
    int* blocksums = (int*)alloc(64 * 4);

    // ---- CSR build (by dst) ----
    hipMemsetAsync(counts, 0, (size_t)N * 4, stream);
    count_dst<<<(E + 255) / 256, 256, 0, stream>>>(dst, counts, E);
    int nb = (N + 1023) / 1024;  // 49
    scan_local<<<nb, 256, 0, stream>>>(counts, indptr, blocksums, N);
    scan_carry<<<1, 64, 0, stream>>>(blocksums, nb);
    scan_add<<<nb, 256, 0, stream>>>(indptr, blocksums, N, E);
    hipMemcpyAsync(cursor, indptr, (size_t)N * 4, hipMemcpyDeviceToDevice, stream);
    fill_csr<<<(E + 255) / 256, 256, 0, stream>>>(dst, src, cursor, csrc, E);

    // ---- layer 0 ----
    int mtiles = (N + 63) / 64;  // 782
    gemm_mfma<256, float><<<mtiles, 256, 0, stream>>>(x, W0, h0, N);
    elr_kernel<4><<<(N + 3) / 4, 256, 0, stream>>>(h0, al0, ar0, el0, er0, N);
    agg_kernel<4, true, f16><<<N, 256, 0, stream>>>(h0, el0, er0, b0, indptr, csrc, y, N);

    // ---- layer 1 ----
    gemm_mfma<64, f16><<<mtiles, 256, 0, stream>>>(y, W1, h1, N);
    elr_kernel<1><<<(N + 15) / 16, 256, 0, stream>>>(h1, al1, ar1, el1, er1, N);
    agg_kernel<1, false, float><<<(N + 3) / 4, 256, 0, stream>>>(h1, el1, er1, b1, indptr, csrc, out, N);
}